// Round 15
// baseline (157.195 us; speedup 1.0000x reference)
//
#include <hip/hip_runtime.h>
#include <hip/hip_bf16.h>
#include <math.h>

typedef __attribute__((ext_vector_type(4))) float f32x4;
typedef __attribute__((ext_vector_type(8))) short s16x8;
typedef __hip_bfloat16 bf16;

constexpr int TOK = 2048;   // B*S tokens
constexpr int DIM = 1024;   // hidden D
constexpr int HID = 512;    // expert inter H
constexpr int NE  = 16;     // experts
constexpr int NK  = 4;      // top-k
constexpr int NHS = 1024;   // shared inter HS
constexpr int NPAIR = TOK * NK;  // 8192 token-expert pairs

// Per-XCD job capacity. Worst case: 8 shared + (32+1 segs)*4 routed = 140.
constexpr int CPX = 144;
constexpr int GEMM_GRID = 8 * CPX;  // 1152

#define MFMA(a, b, c) __builtin_amdgcn_mfma_f32_16x16x32_bf16(a, b, c, 0, 0, 0)

#define GLOAD_LDS(gp, lp)                                                        \
  __builtin_amdgcn_global_load_lds(                                              \
      (const __attribute__((address_space(1))) unsigned int*)(gp),               \
      (__attribute__((address_space(3))) unsigned int*)(lp), 16, 0, 0)

// Stage a (CH*64)-row x 64-col bf16 tile into LDS with 512 threads. rp[i] is
// this thread's precomputed row base pointer. LDS slot s of row r holds
// k-chunk s^(r&7): XOR swizzle on the per-lane GLOBAL source; LDS dest linear
// (global_load_lds requirement). 0 bank conflicts measured rounds 2-14.
template <int CH>
static __device__ __forceinline__ void stage_p(const bf16* const* rp, int k0,
                                               bf16* lds, int tid) {
  int wid = tid >> 6;
#pragma unroll
  for (int i = 0; i < CH; ++i) {
    int c = i * 512 + tid;      // 16B-chunk index
    int row = c >> 3;
    int slot = c & 7;
    int j = slot ^ (row & 7);
    const bf16* g = rp[i] + k0 + j * 8;
    bf16* l = lds + (size_t)(i * 512 + wid * 64) * 8;  // wave-uniform base
    GLOAD_LDS(g, l);
  }
}

static __device__ __forceinline__ s16x8 frag(const bf16* lds, int row, int kc) {
  return *(const s16x8*)(lds + row * 64 + ((kc ^ (row & 7)) << 3));
}

static __device__ __forceinline__ float b2f(short u) {
  union { unsigned int i; float f; } c;
  c.i = ((unsigned int)(unsigned short)u) << 16;
  return c.f;
}

struct bf16x4 { bf16 a, b, c, d; };
struct alignas(16) bf16x8 { bf16 v[8]; };

// ---------------- vectorized transpose+cast: 64x64 tiles ----------------

static __device__ __forceinline__ void tr64(const float* __restrict__ src,
                                            bf16* __restrict__ dst, int R, int C,
                                            int bx, int by, float (*t)[65], int tid) {
  int r0 = by * 64, c0 = bx * 64;
#pragma unroll
  for (int i = 0; i < 4; ++i) {
    int row = i * 16 + (tid >> 4);
    int col = (tid & 15) * 4;
    float4 v = *(const float4*)(src + (size_t)(r0 + row) * C + c0 + col);
    t[row][col] = v.x; t[row][col + 1] = v.y;
    t[row][col + 2] = v.z; t[row][col + 3] = v.w;
  }
  __syncthreads();
  int c = tid >> 2;             // out-row (source col) 0..63
  int rb = (tid & 3) * 16;      // source-row base
  bf16x8 o0, o1;
#pragma unroll
  for (int k = 0; k < 8; ++k) o0.v[k] = __float2bfloat16(t[rb + k][c]);
#pragma unroll
  for (int k = 0; k < 8; ++k) o1.v[k] = __float2bfloat16(t[rb + 8 + k][c]);
  bf16* d = dst + (size_t)(c0 + c) * R + r0 + rb;
  *(bf16x8*)d = o0;
  *(bf16x8*)(d + 8) = o1;
}

// ---------------- prep1 + fused gate (independent block ranges) -------------

__global__ __launch_bounds__(256) void prep1_gate(
    const float* __restrict__ x, const float* __restrict__ gw,
    bf16* __restrict__ xb, float* __restrict__ scores,
    const float* __restrict__ ws_in, const float* __restrict__ vs_in,
    const float* __restrict__ e_win, const float* __restrict__ e_vin,
    bf16* __restrict__ wsinT, bf16* __restrict__ vsinT,
    bf16* __restrict__ ewinT, bf16* __restrict__ evinT) {
  __shared__ float t[64][65];
  int bid = blockIdx.x, tid = threadIdx.x;
  if (bid < 512) {
    int lane = tid & 63, wid = tid >> 6;
    int tok = bid * 4 + wid;
    const float* xr = x + (size_t)tok * DIM + lane * 16;
    float4 x4[4];
#pragma unroll
    for (int q = 0; q < 4; ++q) x4[q] = *(const float4*)(xr + q * 4);
    bf16* xo = xb + (size_t)tok * DIM + lane * 16;
#pragma unroll
    for (int q = 0; q < 4; ++q) {
      bf16x4 o{__float2bfloat16(x4[q].x), __float2bfloat16(x4[q].y),
               __float2bfloat16(x4[q].z), __float2bfloat16(x4[q].w)};
      *reinterpret_cast<bf16x4*>(xo + q * 4) = o;
    }
    float s[NE];
#pragma unroll
    for (int e = 0; e < NE; ++e) {
      const float* wr_ = gw + (size_t)e * DIM + lane * 16;
      float a = 0.f;
#pragma unroll
      for (int q = 0; q < 4; ++q) {
        float4 w4 = *(const float4*)(wr_ + q * 4);
        a += x4[q].x * w4.x + x4[q].y * w4.y + x4[q].z * w4.z + x4[q].w * w4.w;
      }
      s[e] = a;
    }
#pragma unroll
    for (int e = 0; e < NE; ++e)
#pragma unroll
      for (int off = 32; off; off >>= 1) s[e] += __shfl_xor(s[e], off);
    if (lane == 0) {
#pragma unroll
      for (int e = 0; e < NE; ++e) scores[(size_t)tok * NE + e] = s[e];
    }
    return;
  }
  int b0 = bid - 512;
  if (b0 < 256) {
    tr64(ws_in, wsinT, DIM, NHS, b0 & 15, b0 >> 4, t, tid);
  } else if (b0 < 512) {
    int b = b0 - 256;
    tr64(vs_in, vsinT, DIM, NHS, b & 15, b >> 4, t, tid);
  } else if (b0 < 2560) {
    int b = b0 - 512, e = b >> 7; b &= 127;
    tr64(e_win + (size_t)e * DIM * HID, ewinT + (size_t)e * DIM * HID,
         DIM, HID, b & 7, b >> 3, t, tid);
  } else {
    int b = b0 - 2560, e = b >> 7; b &= 127;
    tr64(e_vin + (size_t)e * DIM * HID, evinT + (size_t)e * DIM * HID,
         DIM, HID, b & 7, b >> 3, t, tid);
  }
}

__global__ __launch_bounds__(256) void prep2(const float* __restrict__ ws_out,
                                             const float* __restrict__ e_wout,
                                             bf16* __restrict__ wsoutT,
                                             bf16* __restrict__ ewoutT) {
  __shared__ float t[64][65];
  int bid = blockIdx.x, tid = threadIdx.x;
  if (bid < 256) {
    tr64(ws_out, wsoutT, NHS, DIM, bid & 15, bid >> 4, t, tid);
  } else {
    int b = bid - 256, e = b >> 7; b &= 127;
    tr64(e_wout + (size_t)e * HID * DIM, ewoutT + (size_t)e * HID * DIM,
         HID, DIM, b & 15, b >> 4, t, tid);
  }
}

// One THREAD per token: sigmoid + top-4 + LDS histogram -> 16 atomics/block.
__global__ __launch_bounds__(256) void topk_hist(const float* __restrict__ scores,
                                                 int* __restrict__ topi,
                                                 float* __restrict__ topw,
                                                 int* __restrict__ counts) {
  __shared__ int h[NE];
  int tid = threadIdx.x;
  int t = blockIdx.x * 256 + tid;
  if (tid < NE) h[tid] = 0;
  __syncthreads();
  float g[NE];
  const float* sr = scores + (size_t)t * NE;
#pragma unroll
  for (int q = 0; q < 4; ++q) {
    float4 v = *(const float4*)(sr + q * 4);
    g[q * 4 + 0] = 1.f / (1.f + expf(-v.x));
    g[q * 4 + 1] = 1.f / (1.f + expf(-v.y));
    g[q * 4 + 2] = 1.f / (1.f + expf(-v.z));
    g[q * 4 + 3] = 1.f / (1.f + expf(-v.w));
  }
  unsigned used = 0;
  int bi[NK]; float bv[NK];
  float sum = 0.f;
#pragma unroll
  for (int j = 0; j < NK; ++j) {        // lax.top_k tie-break: lowest index first
    int best = 0; float v = -1e30f;
#pragma unroll
    for (int e = 0; e < NE; ++e)
      if (!((used >> e) & 1u) && g[e] > v) { v = g[e]; best = e; }
    used |= 1u << best; bi[j] = best; bv[j] = v; sum += v;
  }
  float inv = 1.f / sum;
#pragma unroll
  for (int j = 0; j < NK; ++j) {
    topi[t * NK + j] = bi[j];
    topw[t * NK + j] = bv[j] * inv;
    atomicAdd(&h[bi[j]], 1);
  }
  __syncthreads();
  if (tid < NE) atomicAdd(&counts[tid], h[tid]);
}

// Offsets + XCD-partitioned job lists for 256-row tiles/segs.
// Job encoding: shared = 0x40000000 | (m<<4) | n0;
//               routed = (e<<12) | (s<<4) | n0   (s = 256-row seg, <=31).
// jobs arrays pre-memset to -1; block exits on jv<0.
__global__ __launch_bounds__(64) void route_small(const int* __restrict__ counts,
                                                  int* __restrict__ offs,
                                                  int* __restrict__ cursor,
                                                  int* __restrict__ jobs_up,
                                                  int* __restrict__ jobs_dn) {
  __shared__ int nseg_s[NE], off_s[NE];
  int t = threadIdx.x;
  if (t == 0) {
    int o = 0;
    for (int e = 0; e < NE; ++e) { off_s[e] = o; o += counts[e]; }
  }
  __syncthreads();
  if (t < NE) {
    offs[t] = off_s[t];
    cursor[t * 32] = 0;
    nseg_s[t] = (counts[t] + 255) >> 8;
  }
  __syncthreads();
  if (t < 8) {             // up shared: XCD m gets all 8 n-tiles of m-tile m
    for (int n = 0; n < 8; ++n)
      jobs_up[t * CPX + n] = 0x40000000 | (t << 4) | n;
  } else if (t < 24) {     // up routed: expert e -> XCD e&7
    int e = t - 8, chunk = e & 7;
    int base = 8 + ((e >= 8) ? 4 * nseg_s[e - 8] : 0);
    for (int s = 0; s < nseg_s[e]; ++s)
      for (int n = 0; n < 4; ++n)
        jobs_up[chunk * CPX + base + s * 4 + n] = (e << 12) | (s << 4) | n;
  } else if (t < 32) {     // down shared: XCD m gets 4 n-tiles of m-tile m
    int m = t - 24;
    for (int n = 0; n < 4; ++n)
      jobs_dn[m * CPX + n] = 0x40000000 | (m << 4) | n;
  } else if (t < 48) {     // down routed
    int e = t - 32, chunk = e & 7;
    int base = 4 + ((e >= 8) ? 4 * nseg_s[e - 8] : 0);
    for (int s = 0; s < nseg_s[e]; ++s)
      for (int n = 0; n < 4; ++n)
        jobs_dn[chunk * CPX + base + s * 4 + n] = (e << 12) | (s << 4) | n;
  }
}

// Parallel compaction via per-expert atomic cursor (cacheline-padded).
__global__ __launch_bounds__(256) void scatter_pairs(const int* __restrict__ topi,
                                                     const float* __restrict__ topw,
                                                     const int* __restrict__ offs,
                                                     int* __restrict__ cursor,
                                                     int* __restrict__ tok_list,
                                                     float* __restrict__ w_list,
                                                     int* __restrict__ pair_slot) {
  int p = blockIdx.x * 256 + threadIdx.x;
  if (p >= NPAIR) return;
  int e = topi[p];
  int rank = atomicAdd(&cursor[e * 32], 1);
  int slot = offs[e] + rank;
  tok_list[slot] = p >> 2;   // token id
  w_list[slot] = topw[p];
  pair_slot[p] = slot;
}

// ---------------- fused up-projection: 256x256 B'-space tile ----------------
// A 256 rows (32K) + B' 256 rows (32K, dbuf -> 96 KB LDS, 1 block/CU).
// 8 waves (2Mx4N), acc[8][4]. Counted-vmcnt pipeline: issue B(k+1) -> wait
// vmcnt(4) (B(k+1) in flight; A(k),B(k) drained) -> barrier -> MFMA ->
// barrier -> stage A(k+1). B' interleaves W1/W2 rows 16-at-a-time; out tile
// = 256 rows x 128 cols.

__global__ __launch_bounds__(512, 2) void up_all(
    const bf16* __restrict__ xb, const bf16* __restrict__ wsinT,
    const bf16* __restrict__ vsinT, const bf16* __restrict__ ewinT,
    const bf16* __restrict__ evinT, const int* __restrict__ tok_list,
    const float* __restrict__ w_list, const int* __restrict__ counts,
    const int* __restrict__ offs, const int* __restrict__ jobs_up,
    bf16* __restrict__ hsb, bf16* __restrict__ hre) {
  int bid = blockIdx.x;
  int jv = jobs_up[(bid & 7) * CPX + (bid >> 3)];
  if (jv < 0) return;
  int tid = threadIdx.x, lane = tid & 63, wid = tid >> 6;
  int wr = wid >> 2, wc = wid & 3;

  bool is_shared = (jv & 0x40000000) != 0;
  int m0, n0, cnt = TOK, off_e = 0;
  const bf16 *w1, *w2;
  if (is_shared) {
    m0 = ((jv >> 4) & 0xFF) * 256; n0 = jv & 15;
    w1 = wsinT; w2 = vsinT;
  } else {
    int e = (jv >> 12) & 15;
    m0 = ((jv >> 4) & 0xFF) * 256; n0 = jv & 15;
    cnt = counts[e]; off_e = offs[e];
    w1 = ewinT + (size_t)e * HID * DIM;
    w2 = evinT + (size_t)e * HID * DIM;
  }

  const bf16* ap[4]; const bf16* bp[4];
#pragma unroll
  for (int i = 0; i < 4; ++i) {
    int row = (i * 512 + tid) >> 3;  // 0..255
    int gr = is_shared ? (m0 + row) : tok_list[off_e + min(m0 + row, cnt - 1)];
    ap[i] = xb + (size_t)gr * DIM;
  }
#pragma unroll
  for (int i = 0; i < 4; ++i) {
    int r = (i * 512 + tid) >> 3;    // B'-row 0..255
    int ridx = n0 * 128 + (r >> 5) * 16 + (r & 15);
    bp[i] = ((r & 16) ? w2 : w1) + (size_t)ridx * DIM;
  }

  __shared__ alignas(16) bf16 As[256 * 64], Bs[2][256 * 64];
  f32x4 acc[8][4];
  f32x4 z4 = {0.f, 0.f, 0.f, 0.f};
#pragma unroll
  for (int m = 0; m < 8; ++m)
#pragma unroll
    for (int q = 0; q < 4; ++q) acc[m][q] = z4;

  constexpr int NT = DIM / 64;  // 16
  stage_p<4>(ap, 0, As, tid);
  stage_p<4>(bp, 0, Bs[0], tid);

  for (int kt = 0; kt < NT; ++kt) {
    if (kt + 1 < NT) {
      stage_p<4>(bp, (kt + 1) * 64, Bs[(kt + 1) & 1], tid);
      asm volatile("s_waitcnt vmcnt(4)" ::: "memory");   // B(k+1) stays in flight
    } else {
      asm volatile("s_waitcnt vmcnt(0)" ::: "memory");
    }
    __builtin_amdgcn_sched_barrier(0);
    __builtin_amdgcn_s_barrier();
    __builtin_amdgcn_sched_barrier(0);
    const bf16* Bc = Bs[kt & 1];
    __builtin_amdgcn_s_setprio(1);
#pragma unroll
    for (int ks = 0; ks < 2; ++ks) {
      int r16 = lane & 15, kc = (ks << 2) + (lane >> 4);
      s16x8 a[8];
#pragma unroll
      for (int m = 0; m < 8; ++m) a[m] = frag(As, wr * 128 + m * 16 + r16, kc);
#pragma unroll
      for (int q = 0; q < 4; ++q) {
        s16x8 b = frag(Bc, wc * 64 + q * 16 + r16, kc);
#pragma unroll
        for (int m = 0; m < 8; ++m) acc[m][q] = MFMA(a[m], b, acc[m][q]);
      }
    }
    __builtin_amdgcn_s_setprio(0);
    __builtin_amdgcn_sched_barrier(0);
    __builtin_amdgcn_s_barrier();
    __builtin_amdgcn_sched_barrier(0);
    if (kt + 1 < NT) stage_p<4>(ap, (kt + 1) * 64, As, tid);
  }
#pragma unroll
  for (int m = 0; m < 8; ++m)
#pragma unroll
    for (int q = 0; q < 4; q += 2) {
      int c = n0 * 128 + (wc * 2 + (q >> 1)) * 16 + (lane & 15);
#pragma unroll
      for (int i = 0; i < 4; ++i) {
        int r = wr * 128 + m * 16 + (lane >> 4) * 4 + i;
        float z = acc[m][q][i], v = acc[m][q + 1][i];
        float h = z / (1.f + __expf(-z)) * v;
        if (is_shared) {
          hsb[(size_t)(m0 + r) * NHS + c] = __float2bfloat16(h);
        } else {
          int gr = m0 + r;
          if (gr < cnt)
            hre[(size_t)(off_e + gr) * HID + c] =
                __float2bfloat16(h * w_list[off_e + gr]);
        }
      }
    }
}

// ---------------- fused down-projection: 256x256 tile, NO atomics -----------
// Shared jobs plain-store their unique 256x256 out tile; routed jobs store
// bf16 rows into hrd[slot][DIM] (aliases dead evinT); finish_add reduces.

__global__ __launch_bounds__(512, 2) void down_all(
    const bf16* __restrict__ hsb, const bf16* __restrict__ wsoutT,
    const bf16* __restrict__ hre, const bf16* __restrict__ ewoutT,
    const int* __restrict__ tok_list, const int* __restrict__ counts,
    const int* __restrict__ offs, const int* __restrict__ jobs_dn,
    float* __restrict__ out, bf16* __restrict__ hrd) {
  int bid = blockIdx.x;
  int jv = jobs_dn[(bid & 7) * CPX + (bid >> 3)];
  if (jv < 0) return;
  int tid = threadIdx.x, lane = tid & 63, wid = tid >> 6;
  int wr = wid >> 2, wc = wid & 3;

  bool is_shared = (jv & 0x40000000) != 0;
  int m0, n0, cnt = TOK, off_e = 0, K, ldA, ldB;
  const bf16 *Abase, *Bbase;
  if (is_shared) {
    m0 = ((jv >> 4) & 0xFF) * 256; n0 = jv & 15;
    Abase = hsb; ldA = NHS; K = NHS;
    Bbase = wsoutT; ldB = NHS;
  } else {
    int e = (jv >> 12) & 15;
    m0 = ((jv >> 4) & 0xFF) * 256; n0 = jv & 15;
    cnt = counts[e]; off_e = offs[e];
    Abase = hre + (size_t)off_e * HID; ldA = HID; K = HID;
    Bbase = ewoutT + (size_t)e * DIM * HID; ldB = HID;
  }

  const bf16* ap[4]; const bf16* bp[4];
#pragma unroll
  for (int i = 0; i < 4; ++i) {
    int row = (i * 512 + tid) >> 3;  // 0..255
    int gr = is_shared ? (m0 + row) : min(m0 + row, cnt - 1);
    ap[i] = Abase + (size_t)gr * ldA;
  }
#pragma unroll
  for (int i = 0; i < 4; ++i) {
    int r = (i * 512 + tid) >> 3;    // 0..255
    bp[i] = Bbase + (size_t)(n0 * 256 + r) * ldB;
  }

  __shared__ alignas(16) bf16 As[256 * 64], Bs[2][256 * 64];
  f32x4 acc[8][4];
  f32x4 z4 = {0.f, 0.f, 0.f, 0.f};
#pragma unroll
  for (int m = 0; m < 8; ++m)
#pragma unroll
    for (int q = 0; q < 4; ++q) acc[m][q] = z4;

  int NT = K / 64;
  stage_p<4>(ap, 0, As, tid);
  stage_p<4>(bp, 0, Bs[0], tid);

  for (int kt = 0; kt < NT; ++kt) {
    if (kt + 1 < NT) {
      stage_p<4>(bp, (kt + 1) * 64, Bs[(kt + 1) & 1], tid);
      asm volatile("s_waitcnt vmcnt(4)" ::: "memory");
    } else {
      asm volatile("s_waitcnt vmcnt(0)" ::: "memory");
    }
    __builtin_amdgcn_sched_barrier(0);
    __builtin_amdgcn_s_barrier();
    __builtin_amdgcn_sched_barrier(0);
    const bf16* Bc = Bs[kt & 1];
    __builtin_amdgcn_s_setprio(1);
#pragma unroll
    for (int ks = 0; ks < 2; ++ks) {
      int r16 = lane & 15, kc = (ks << 2) + (lane >> 4);
      s16x8 a[8];
#pragma unroll
      for (int m = 0; m < 8; ++m) a[m] = frag(As, wr * 128 + m * 16 + r16, kc);
#pragma unroll
      for (int q = 0; q < 4; ++q) {
        s16x8 b = frag(Bc, wc * 64 + q * 16 + r16, kc);
#pragma unroll
        for (int m = 0; m < 8; ++m) acc[m][q] = MFMA(a[m], b, acc[m][q]);
      }
    }
    __builtin_amdgcn_s_setprio(0);
    __builtin_amdgcn_sched_barrier(0);
    __builtin_amdgcn_s_barrier();
    __builtin_amdgcn_sched_barrier(0);
    if (kt + 1 < NT) stage_p<4>(ap, (kt + 1) * 64, As, tid);
  }
#pragma unroll
  for (int m = 0; m < 8; ++m)
#pragma unroll
    for (int q = 0; q < 4; ++q) {
      int c = n0 * 256 + wc * 64 + q * 16 + (lane & 15);
#pragma unroll
      for (int i = 0; i < 4; ++i) {
        int r = wr * 128 + m * 16 + (lane >> 4) * 4 + i;
        if (is_shared) {
          out[(size_t)(m0 + r) * DIM + c] = acc[m][q][i];
        } else {
          int gr = m0 + r;
          if (gr < cnt)
            hrd[(size_t)(off_e + gr) * DIM + c] = __float2bfloat16(acc[m][q][i]);
        }
      }
    }
}

// ---------------- final gather-reduce: out[t] += sum of 4 routed rows -------

__global__ __launch_bounds__(256) void finish_add(const bf16* __restrict__ hrd,
                                                  const int* __restrict__ pair_slot,
                                                  float* __restrict__ out) {
  int idx = blockIdx.x * 256 + threadIdx.x;
  int t = idx >> 7;            // DIM/8 = 128 chunks per token
  int c0 = (idx & 127) * 8;
  int4 s4 = *(const int4*)(pair_slot + t * 4);
  float acc[8];
  float* o = out + (size_t)t * DIM + c0;
#pragma unroll
  for (int k = 0; k < 8; ++k) acc[k] = o[k];
  int sl[4] = {s4.x, s4.y, s4.z, s4.w};
#pragma unroll
  for (int j = 0; j < 4; ++j) {
    s16x8 v = *(const s16x8*)(hrd + (size_t)sl[j] * DIM + c0);
#pragma unroll
    for (int k = 0; k < 8; ++k) acc[k] += b2f(v[k]);
  }
#pragma unroll
  for (int k = 0; k < 8; ++k) o[k] = acc[k];
}

// ---------------- launcher ----------------

extern "C" void kernel_launch(void* const* d_in, const int* in_sizes, int n_in,
                              void* d_out, int out_size, void* d_ws, size_t ws_size,
                              hipStream_t stream) {
  const float* x      = (const float*)d_in[0];
  const float* gw     = (const float*)d_in[1];
  const float* ws_in  = (const float*)d_in[2];
  const float* vs_in  = (const float*)d_in[3];
  const float* ws_out = (const float*)d_in[4];
  const float* e_win  = (const float*)d_in[5];
  const float* e_vin  = (const float*)d_in[6];
  const float* e_wout = (const float*)d_in[7];
  float* out = (float*)d_out;

  // Workspace layout, peak ~52.7 MB (validated fits in rounds 2-14).
  char* p = (char*)d_ws;
  bf16* xb     = (bf16*)p;  p += (size_t)TOK * DIM * 2;            // 4 MB
  bf16* wsinT  = (bf16*)p;                                         // 2 MB
  bf16* wsoutT = wsinT;                                            // reused after up_all
  p += (size_t)NHS * DIM * 2;
  bf16* vsinT  = (bf16*)p;  p += (size_t)NHS * DIM * 2;            // 2 MB
  bf16* hsb    = (bf16*)p;  p += (size_t)TOK * NHS * 2;            // 4 MB
  bf16* ewinT  = (bf16*)p;                                         // 16 MB
  bf16* ewoutT = ewinT;                                            // reused after up_all
  p += (size_t)NE * DIM * HID * 2;
  bf16* evinT  = (bf16*)p;                                         // 16 MB
  bf16* hrd    = evinT;  // routed down-proj rows; NPAIR*DIM*2 = exactly 16 MiB
  p += (size_t)NE * DIM * HID * 2;
  bf16* hre    = (bf16*)p;  p += (size_t)(NPAIR + 256) * HID * 2;  // 8.3 MB
  int*   topi      = (int*)p;    p += (size_t)NPAIR * 4;
  float* topw      = (float*)p;  p += (size_t)NPAIR * 4;
  int*   tok_list  = (int*)p;    p += (size_t)NPAIR * 4;
  float* w_list    = (float*)p;  p += (size_t)NPAIR * 4;
  int*   pair_slot = (int*)p;    p += (size_t)NPAIR * 4;
  float* scores    = (float*)p;  p += (size_t)TOK * NE * 4;        // 128 KB
  int*   counts    = (int*)p;    p += 64;
  int*   offs      = (int*)p;    p += 64;
  int*   cursor    = (int*)p;    p += NE * 32 * 4;                 // 1 line/expert
  int*   jobs_up   = (int*)p;    p += GEMM_GRID * 4;
  int*   jobs_dn   = (int*)p;    p += GEMM_GRID * 4;

  hipMemsetAsync(counts, 0, NE * sizeof(int), stream);
  hipMemsetAsync(jobs_up, 0xFF, GEMM_GRID * sizeof(int), stream);
  hipMemsetAsync(jobs_dn, 0xFF, GEMM_GRID * sizeof(int), stream);

  prep1_gate<<<5120, 256, 0, stream>>>(x, gw, xb, scores, ws_in, vs_in,
                                       e_win, e_vin, wsinT, vsinT, ewinT, evinT);
  topk_hist<<<TOK / 256, 256, 0, stream>>>(scores, topi, topw, counts);
  route_small<<<1, 64, 0, stream>>>(counts, offs, cursor, jobs_up, jobs_dn);
  scatter_pairs<<<NPAIR / 256, 256, 0, stream>>>(topi, topw, offs, cursor,
                                                 tok_list, w_list, pair_slot);

  up_all<<<GEMM_GRID, 512, 0, stream>>>(xb, wsinT, vsinT, ewinT, evinT, tok_list,
                                        w_list, counts, offs, jobs_up, hsb, hre);

  // ws_out/e_wout transposes overwrite wsinT/ewinT (dead after up_all).
  prep2<<<2304, 256, 0, stream>>>(ws_out, e_wout, wsoutT, ewoutT);

  // down: shared jobs plain-store out; routed jobs plain-store hrd (=evinT).
  down_all<<<GEMM_GRID, 512, 0, stream>>>(hsb, wsoutT, hre, ewoutT, tok_list,
                                          counts, offs, jobs_dn, out, hrd);
  finish_add<<<TOK * DIM / 8 / 256, 256, 0, stream>>>(hrd, pair_slot, out);
}

// Round 16
// 143.675 us; speedup vs baseline: 1.0941x; 1.0941x over previous
//
#include <hip/hip_runtime.h>
#include <hip/hip_bf16.h>
#include <math.h>

typedef __attribute__((ext_vector_type(4))) float f32x4;
typedef __attribute__((ext_vector_type(8))) short s16x8;
typedef __hip_bfloat16 bf16;

constexpr int TOK = 2048;   // B*S tokens
constexpr int DIM = 1024;   // hidden D
constexpr int HID = 512;    // expert inter H
constexpr int NE  = 16;     // experts
constexpr int NK  = 4;      // top-k
constexpr int NHS = 1024;   // shared inter HS
constexpr int NPAIR = TOK * NK;  // 8192 token-expert pairs

// 128-row segs worst case: sum(ceil(cnt_e/128)) <= 16 + 8192/128 = 80
constexpr int UP_GRID = 256 + 8 * 80;  // 896 (mult of 8)
constexpr int DN_GRID = 128 + 8 * 80;  // 768 (mult of 8)

#define MFMA(a, b, c) __builtin_amdgcn_mfma_f32_16x16x32_bf16(a, b, c, 0, 0, 0)

#define GLOAD_LDS(gp, lp)                                                        \
  __builtin_amdgcn_global_load_lds(                                              \
      (const __attribute__((address_space(1))) unsigned int*)(gp),               \
      (__attribute__((address_space(3))) unsigned int*)(lp), 16, 0, 0)

// Stage a (CH*64)-row x 64-col bf16 tile into LDS with 512 threads. rp[i] is
// this thread's precomputed row base pointer. LDS slot s of row r holds
// k-chunk s^(r&7): XOR swizzle on the per-lane GLOBAL source; LDS dest linear
// (global_load_lds requirement). 0 bank conflicts measured rounds 2-15.
template <int CH>
static __device__ __forceinline__ void stage_p(const bf16* const* rp, int k0,
                                               bf16* lds, int tid) {
  int wid = tid >> 6;
#pragma unroll
  for (int i = 0; i < CH; ++i) {
    int c = i * 512 + tid;      // 16B-chunk index
    int row = c >> 3;
    int slot = c & 7;
    int j = slot ^ (row & 7);
    const bf16* g = rp[i] + k0 + j * 8;
    bf16* l = lds + (size_t)(i * 512 + wid * 64) * 8;  // wave-uniform base
    GLOAD_LDS(g, l);
  }
}

static __device__ __forceinline__ s16x8 frag(const bf16* lds, int row, int kc) {
  return *(const s16x8*)(lds + row * 64 + ((kc ^ (row & 7)) << 3));
}

static __device__ __forceinline__ float b2f(short u) {
  union { unsigned int i; float f; } c;
  c.i = ((unsigned int)(unsigned short)u) << 16;
  return c.f;
}

struct bf16x4 { bf16 a, b, c, d; };
struct alignas(16) bf16x8 { bf16 v[8]; };

// ---------------- vectorized transpose+cast: 64x64 tiles ----------------

static __device__ __forceinline__ void tr64(const float* __restrict__ src,
                                            bf16* __restrict__ dst, int R, int C,
                                            int bx, int by, float (*t)[65], int tid) {
  int r0 = by * 64, c0 = bx * 64;
#pragma unroll
  for (int i = 0; i < 4; ++i) {
    int row = i * 16 + (tid >> 4);
    int col = (tid & 15) * 4;
    float4 v = *(const float4*)(src + (size_t)(r0 + row) * C + c0 + col);
    t[row][col] = v.x; t[row][col + 1] = v.y;
    t[row][col + 2] = v.z; t[row][col + 3] = v.w;
  }
  __syncthreads();
  int c = tid >> 2;             // out-row (source col) 0..63
  int rb = (tid & 3) * 16;      // source-row base
  bf16x8 o0, o1;
#pragma unroll
  for (int k = 0; k < 8; ++k) o0.v[k] = __float2bfloat16(t[rb + k][c]);
#pragma unroll
  for (int k = 0; k < 8; ++k) o1.v[k] = __float2bfloat16(t[rb + 8 + k][c]);
  bf16* d = dst + (size_t)(c0 + c) * R + r0 + rb;
  *(bf16x8*)d = o0;
  *(bf16x8*)(d + 8) = o1;
}

// ---------------- prep1 + fused gate (independent block ranges) -------------

__global__ __launch_bounds__(256) void prep1_gate(
    const float* __restrict__ x, const float* __restrict__ gw,
    bf16* __restrict__ xb, float* __restrict__ scores,
    const float* __restrict__ ws_in, const float* __restrict__ vs_in,
    const float* __restrict__ e_win, const float* __restrict__ e_vin,
    bf16* __restrict__ wsinT, bf16* __restrict__ vsinT,
    bf16* __restrict__ ewinT, bf16* __restrict__ evinT) {
  __shared__ float t[64][65];
  int bid = blockIdx.x, tid = threadIdx.x;
  if (bid < 512) {
    int lane = tid & 63, wid = tid >> 6;
    int tok = bid * 4 + wid;
    const float* xr = x + (size_t)tok * DIM + lane * 16;
    float4 x4[4];
#pragma unroll
    for (int q = 0; q < 4; ++q) x4[q] = *(const float4*)(xr + q * 4);
    bf16* xo = xb + (size_t)tok * DIM + lane * 16;
#pragma unroll
    for (int q = 0; q < 4; ++q) {
      bf16x4 o{__float2bfloat16(x4[q].x), __float2bfloat16(x4[q].y),
               __float2bfloat16(x4[q].z), __float2bfloat16(x4[q].w)};
      *reinterpret_cast<bf16x4*>(xo + q * 4) = o;
    }
    float s[NE];
#pragma unroll
    for (int e = 0; e < NE; ++e) {
      const float* wr_ = gw + (size_t)e * DIM + lane * 16;
      float a = 0.f;
#pragma unroll
      for (int q = 0; q < 4; ++q) {
        float4 w4 = *(const float4*)(wr_ + q * 4);
        a += x4[q].x * w4.x + x4[q].y * w4.y + x4[q].z * w4.z + x4[q].w * w4.w;
      }
      s[e] = a;
    }
#pragma unroll
    for (int e = 0; e < NE; ++e)
#pragma unroll
      for (int off = 32; off; off >>= 1) s[e] += __shfl_xor(s[e], off);
    if (lane == 0) {
#pragma unroll
      for (int e = 0; e < NE; ++e) scores[(size_t)tok * NE + e] = s[e];
    }
    return;
  }
  int b0 = bid - 512;
  if (b0 < 256) {
    tr64(ws_in, wsinT, DIM, NHS, b0 & 15, b0 >> 4, t, tid);
  } else if (b0 < 512) {
    int b = b0 - 256;
    tr64(vs_in, vsinT, DIM, NHS, b & 15, b >> 4, t, tid);
  } else if (b0 < 2560) {
    int b = b0 - 512, e = b >> 7; b &= 127;
    tr64(e_win + (size_t)e * DIM * HID, ewinT + (size_t)e * DIM * HID,
         DIM, HID, b & 7, b >> 3, t, tid);
  } else {
    int b = b0 - 2560, e = b >> 7; b &= 127;
    tr64(e_vin + (size_t)e * DIM * HID, evinT + (size_t)e * DIM * HID,
         DIM, HID, b & 7, b >> 3, t, tid);
  }
}

__global__ __launch_bounds__(256) void prep2(const float* __restrict__ ws_out,
                                             const float* __restrict__ e_wout,
                                             bf16* __restrict__ wsoutT,
                                             bf16* __restrict__ ewoutT) {
  __shared__ float t[64][65];
  int bid = blockIdx.x, tid = threadIdx.x;
  if (bid < 256) {
    tr64(ws_out, wsoutT, NHS, DIM, bid & 15, bid >> 4, t, tid);
  } else {
    int b = bid - 256, e = b >> 7; b &= 127;
    tr64(e_wout + (size_t)e * HID * DIM, ewoutT + (size_t)e * HID * DIM,
         HID, DIM, b & 15, b >> 4, t, tid);
  }
}

// One THREAD per token: sigmoid + top-4 + LDS histogram -> 16 atomics/block.
__global__ __launch_bounds__(256) void topk_hist(const float* __restrict__ scores,
                                                 int* __restrict__ topi,
                                                 float* __restrict__ topw,
                                                 int* __restrict__ counts) {
  __shared__ int h[NE];
  int tid = threadIdx.x;
  int t = blockIdx.x * 256 + tid;
  if (tid < NE) h[tid] = 0;
  __syncthreads();
  float g[NE];
  const float* sr = scores + (size_t)t * NE;
#pragma unroll
  for (int q = 0; q < 4; ++q) {
    float4 v = *(const float4*)(sr + q * 4);
    g[q * 4 + 0] = 1.f / (1.f + expf(-v.x));
    g[q * 4 + 1] = 1.f / (1.f + expf(-v.y));
    g[q * 4 + 2] = 1.f / (1.f + expf(-v.z));
    g[q * 4 + 3] = 1.f / (1.f + expf(-v.w));
  }
  unsigned used = 0;
  int bi[NK]; float bv[NK];
  float sum = 0.f;
#pragma unroll
  for (int j = 0; j < NK; ++j) {        // lax.top_k tie-break: lowest index first
    int best = 0; float v = -1e30f;
#pragma unroll
    for (int e = 0; e < NE; ++e)
      if (!((used >> e) & 1u) && g[e] > v) { v = g[e]; best = e; }
    used |= 1u << best; bi[j] = best; bv[j] = v; sum += v;
  }
  float inv = 1.f / sum;
#pragma unroll
  for (int j = 0; j < NK; ++j) {
    topi[t * NK + j] = bi[j];
    topw[t * NK + j] = bv[j] * inv;
    atomicAdd(&h[bi[j]], 1);
  }
  __syncthreads();
  if (tid < NE) atomicAdd(&counts[tid], h[tid]);
}

// Tiny serial kernel: offsets, 128-row segment list, cursor reset.
__global__ __launch_bounds__(64) void route_small(const int* __restrict__ counts,
                                                  int* __restrict__ offs,
                                                  int* __restrict__ segs,
                                                  int* __restrict__ nseg,
                                                  int* __restrict__ cursor) {
  if (threadIdx.x != 0) return;
  int o = 0;
#pragma unroll
  for (int e = 0; e < NE; ++e) { offs[e] = o; cursor[e * 32] = 0; o += counts[e]; }
  int s = 0;
  for (int e = 0; e < NE; ++e)
    for (int m = 0; m < counts[e]; m += 128) segs[s++] = (e << 16) | m;
  nseg[0] = s;
}

// Parallel compaction via per-expert atomic cursor (cacheline-padded).
__global__ __launch_bounds__(256) void scatter_pairs(const int* __restrict__ topi,
                                                     const float* __restrict__ topw,
                                                     const int* __restrict__ offs,
                                                     int* __restrict__ cursor,
                                                     int* __restrict__ tok_list,
                                                     float* __restrict__ w_list,
                                                     int* __restrict__ pair_slot) {
  int p = blockIdx.x * 256 + threadIdx.x;
  if (p >= NPAIR) return;
  int e = topi[p];
  int rank = atomicAdd(&cursor[e * 32], 1);
  int slot = offs[e] + rank;
  tok_list[slot] = p >> 2;   // token id
  w_list[slot] = topw[p];
  pair_slot[p] = slot;
}

// ---------------- fused up-projection: 128x128 tile, 32 KB LDS --------------
// A 128 rows + B' 128 rows (=64 out cols, W1/W2 interleaved 16-at-a-time).
// 8 waves (2Mx4N), acc[4][2], single-buffered 2-barrier loop; grid ~3/CU so
// cross-block overlap (m114 mechanism) provides the latency hiding.
// Job space: [0,256): shared (16 m x 16 n'), K=1024.
//            [256, 256+8*nseg): routed seg x 8 n'-tiles, K=1024.

__global__ __launch_bounds__(512, 4) void up_all(
    const bf16* __restrict__ xb, const bf16* __restrict__ wsinT,
    const bf16* __restrict__ vsinT, const bf16* __restrict__ ewinT,
    const bf16* __restrict__ evinT, const int* __restrict__ tok_list,
    const float* __restrict__ w_list, const int* __restrict__ counts,
    const int* __restrict__ offs, const int* __restrict__ segs,
    const int* __restrict__ nseg, bf16* __restrict__ hsb,
    bf16* __restrict__ hre) {
  int bid = blockIdx.x;
  int j = (bid & 7) * (UP_GRID / 8) + (bid >> 3);  // XCD-chunked job swizzle
  int nj = 256 + 8 * nseg[0];
  if (j >= nj) return;
  int tid = threadIdx.x, lane = tid & 63, wid = tid >> 6;
  int wr = wid >> 2, wc = wid & 3;

  bool is_shared = (j < 256);
  int m0, n0, cnt = TOK, off_e = 0;
  const bf16 *w1, *w2;
  if (is_shared) {
    m0 = (j >> 4) * 128; n0 = j & 15;
    w1 = wsinT; w2 = vsinT;
  } else {
    int r = j - 256;
    int sv = segs[r >> 3]; n0 = r & 7;
    int e = sv >> 16; m0 = sv & 0xffff;
    cnt = counts[e]; off_e = offs[e];
    w1 = ewinT + (size_t)e * HID * DIM;
    w2 = evinT + (size_t)e * HID * DIM;
  }

  const bf16* ap[2]; const bf16* bp[2];
#pragma unroll
  for (int i = 0; i < 2; ++i) {
    int row = (i * 512 + tid) >> 3;  // 0..127
    int gr = is_shared ? (m0 + row) : tok_list[off_e + min(m0 + row, cnt - 1)];
    ap[i] = xb + (size_t)gr * DIM;
  }
#pragma unroll
  for (int i = 0; i < 2; ++i) {
    int r = (i * 512 + tid) >> 3;    // B'-row 0..127
    int ridx = n0 * 64 + (r >> 5) * 16 + (r & 15);
    bp[i] = ((r & 16) ? w2 : w1) + (size_t)ridx * DIM;
  }

  __shared__ alignas(16) bf16 As[128 * 64], Bs[128 * 64];
  f32x4 acc[4][2];
  f32x4 z4 = {0.f, 0.f, 0.f, 0.f};
#pragma unroll
  for (int m = 0; m < 4; ++m) { acc[m][0] = z4; acc[m][1] = z4; }

  for (int k0 = 0; k0 < DIM; k0 += 64) {
    __syncthreads();
    stage_p<2>(ap, k0, As, tid);
    stage_p<2>(bp, k0, Bs, tid);
    __syncthreads();
#pragma unroll
    for (int ks = 0; ks < 2; ++ks) {
      int r16 = lane & 15, kc = (ks << 2) + (lane >> 4);
      s16x8 a[4];
#pragma unroll
      for (int m = 0; m < 4; ++m) a[m] = frag(As, wr * 64 + m * 16 + r16, kc);
#pragma unroll
      for (int q = 0; q < 2; ++q) {
        s16x8 b = frag(Bs, wc * 32 + q * 16 + r16, kc);
#pragma unroll
        for (int m = 0; m < 4; ++m) acc[m][q] = MFMA(a[m], b, acc[m][q]);
      }
    }
  }
  int c = n0 * 64 + wc * 16 + (lane & 15);
#pragma unroll
  for (int m = 0; m < 4; ++m)
#pragma unroll
    for (int i = 0; i < 4; ++i) {
      int r = wr * 64 + m * 16 + (lane >> 4) * 4 + i;
      float z = acc[m][0][i], v = acc[m][1][i];
      float h = z / (1.f + __expf(-z)) * v;
      if (is_shared) {
        hsb[(size_t)(m0 + r) * NHS + c] = __float2bfloat16(h);
      } else {
        int gr = m0 + r;
        if (gr < cnt)
          hre[(size_t)(off_e + gr) * HID + c] =
              __float2bfloat16(h * w_list[off_e + gr]);
      }
    }
}

// ---------------- fused down-projection: 128x128 tile, NO atomics -----------
// Shared jobs plain-store their unique 128x128 out tile; routed jobs store
// bf16 rows into hrd[slot][DIM] (aliases dead evinT); finish_add reduces.
// Job space: [0,128): shared (16 m x 8 n), K=1024.
//            [128, 128+8*nseg): routed seg x 8 n-tiles, K=512.

__global__ __launch_bounds__(512, 4) void down_all(
    const bf16* __restrict__ hsb, const bf16* __restrict__ wsoutT,
    const bf16* __restrict__ hre, const bf16* __restrict__ ewoutT,
    const int* __restrict__ tok_list, const int* __restrict__ counts,
    const int* __restrict__ offs, const int* __restrict__ segs,
    const int* __restrict__ nseg, float* __restrict__ out,
    bf16* __restrict__ hrd) {
  int bid = blockIdx.x;
  int j = (bid & 7) * (DN_GRID / 8) + (bid >> 3);
  int nj = 128 + 8 * nseg[0];
  if (j >= nj) return;
  int tid = threadIdx.x, lane = tid & 63, wid = tid >> 6;
  int wr = wid >> 2, wc = wid & 3;

  bool is_shared = (j < 128);
  int m0, n0, cnt = TOK, off_e = 0, K, ldA, ldB;
  const bf16 *Abase, *Bbase;
  if (is_shared) {
    m0 = (j >> 3) * 128; n0 = j & 7;
    Abase = hsb; ldA = NHS; K = NHS;
    Bbase = wsoutT; ldB = NHS;
  } else {
    int r = j - 128;
    int sv = segs[r >> 3]; n0 = r & 7;
    int e = sv >> 16; m0 = sv & 0xffff;
    cnt = counts[e]; off_e = offs[e];
    Abase = hre + (size_t)off_e * HID; ldA = HID; K = HID;
    Bbase = ewoutT + (size_t)e * DIM * HID; ldB = HID;
  }

  const bf16* ap[2]; const bf16* bp[2];
#pragma unroll
  for (int i = 0; i < 2; ++i) {
    int row = (i * 512 + tid) >> 3;  // 0..127
    int gr = is_shared ? (m0 + row) : min(m0 + row, cnt - 1);
    ap[i] = Abase + (size_t)gr * ldA;
  }
#pragma unroll
  for (int i = 0; i < 2; ++i) {
    int r = (i * 512 + tid) >> 3;    // 0..127
    bp[i] = Bbase + (size_t)(n0 * 128 + r) * ldB;
  }

  __shared__ alignas(16) bf16 As[128 * 64], Bs[128 * 64];
  f32x4 acc[4][2];
  f32x4 z4 = {0.f, 0.f, 0.f, 0.f};
#pragma unroll
  for (int m = 0; m < 4; ++m) { acc[m][0] = z4; acc[m][1] = z4; }

  int NT = K / 64;
  for (int kt = 0; kt < NT; ++kt) {
    int k0 = kt * 64;
    __syncthreads();
    stage_p<2>(ap, k0, As, tid);
    stage_p<2>(bp, k0, Bs, tid);
    __syncthreads();
#pragma unroll
    for (int ks = 0; ks < 2; ++ks) {
      int r16 = lane & 15, kc = (ks << 2) + (lane >> 4);
      s16x8 a[4];
#pragma unroll
      for (int m = 0; m < 4; ++m) a[m] = frag(As, wr * 64 + m * 16 + r16, kc);
#pragma unroll
      for (int q = 0; q < 2; ++q) {
        s16x8 b = frag(Bs, wc * 32 + q * 16 + r16, kc);
#pragma unroll
        for (int m = 0; m < 4; ++m) acc[m][q] = MFMA(a[m], b, acc[m][q]);
      }
    }
  }
#pragma unroll
  for (int q = 0; q < 2; ++q) {
    int c = n0 * 128 + wc * 32 + q * 16 + (lane & 15);
#pragma unroll
    for (int m = 0; m < 4; ++m)
#pragma unroll
      for (int i = 0; i < 4; ++i) {
        int r = wr * 64 + m * 16 + (lane >> 4) * 4 + i;
        if (is_shared) {
          out[(size_t)(m0 + r) * DIM + c] = acc[m][q][i];
        } else {
          int gr = m0 + r;
          if (gr < cnt)
            hrd[(size_t)(off_e + gr) * DIM + c] = __float2bfloat16(acc[m][q][i]);
        }
      }
  }
}

// ---------------- final gather-reduce: out[t] += sum of 4 routed rows -------

__global__ __launch_bounds__(256) void finish_add(const bf16* __restrict__ hrd,
                                                  const int* __restrict__ pair_slot,
                                                  float* __restrict__ out) {
  int idx = blockIdx.x * 256 + threadIdx.x;
  int t = idx >> 7;            // DIM/8 = 128 chunks per token
  int c0 = (idx & 127) * 8;
  int4 s4 = *(const int4*)(pair_slot + t * 4);
  float acc[8];
  float* o = out + (size_t)t * DIM + c0;
#pragma unroll
  for (int k = 0; k < 8; ++k) acc[k] = o[k];
  int sl[4] = {s4.x, s4.y, s4.z, s4.w};
#pragma unroll
  for (int j = 0; j < 4; ++j) {
    s16x8 v = *(const s16x8*)(hrd + (size_t)sl[j] * DIM + c0);
#pragma unroll
    for (int k = 0; k < 8; ++k) acc[k] += b2f(v[k]);
  }
#pragma unroll
  for (int k = 0; k < 8; ++k) o[k] = acc[k];
}

// ---------------- launcher ----------------

extern "C" void kernel_launch(void* const* d_in, const int* in_sizes, int n_in,
                              void* d_out, int out_size, void* d_ws, size_t ws_size,
                              hipStream_t stream) {
  const float* x      = (const float*)d_in[0];
  const float* gw     = (const float*)d_in[1];
  const float* ws_in  = (const float*)d_in[2];
  const float* vs_in  = (const float*)d_in[3];
  const float* ws_out = (const float*)d_in[4];
  const float* e_win  = (const float*)d_in[5];
  const float* e_vin  = (const float*)d_in[6];
  const float* e_wout = (const float*)d_in[7];
  float* out = (float*)d_out;

  // Workspace layout, peak ~52.7 MB (validated fits in rounds 2-15).
  char* p = (char*)d_ws;
  bf16* xb     = (bf16*)p;  p += (size_t)TOK * DIM * 2;            // 4 MB
  bf16* wsinT  = (bf16*)p;                                         // 2 MB
  bf16* wsoutT = wsinT;                                            // reused after up_all
  p += (size_t)NHS * DIM * 2;
  bf16* vsinT  = (bf16*)p;  p += (size_t)NHS * DIM * 2;            // 2 MB
  bf16* hsb    = (bf16*)p;  p += (size_t)TOK * NHS * 2;            // 4 MB
  bf16* ewinT  = (bf16*)p;                                         // 16 MB
  bf16* ewoutT = ewinT;                                            // reused after up_all
  p += (size_t)NE * DIM * HID * 2;
  bf16* evinT  = (bf16*)p;                                         // 16 MB
  bf16* hrd    = evinT;  // routed down-proj rows; NPAIR*DIM*2 = exactly 16 MiB
  p += (size_t)NE * DIM * HID * 2;
  bf16* hre    = (bf16*)p;  p += (size_t)(NPAIR + 128) * HID * 2;  // 8.25 MB
  int*   topi      = (int*)p;    p += (size_t)NPAIR * 4;
  float* topw      = (float*)p;  p += (size_t)NPAIR * 4;
  int*   tok_list  = (int*)p;    p += (size_t)NPAIR * 4;
  float* w_list    = (float*)p;  p += (size_t)NPAIR * 4;
  int*   pair_slot = (int*)p;    p += (size_t)NPAIR * 4;
  float* scores    = (float*)p;  p += (size_t)TOK * NE * 4;        // 128 KB
  int*   counts    = (int*)p;    p += 64;
  int*   offs      = (int*)p;    p += 64;
  int*   cursor    = (int*)p;    p += NE * 32 * 4;                 // 1 line/expert
  int*   segs      = (int*)p;    p += 128 * 4;   // worst case 80 segs
  int*   nseg      = (int*)p;    p += 64;

  hipMemsetAsync(counts, 0, NE * sizeof(int), stream);
  prep1_gate<<<5120, 256, 0, stream>>>(x, gw, xb, scores, ws_in, vs_in,
                                       e_win, e_vin, wsinT, vsinT, ewinT, evinT);
  topk_hist<<<TOK / 256, 256, 0, stream>>>(scores, topi, topw, counts);
  route_small<<<1, 64, 0, stream>>>(counts, offs, segs, nseg, cursor);
  scatter_pairs<<<NPAIR / 256, 256, 0, stream>>>(topi, topw, offs, cursor,
                                                 tok_list, w_list, pair_slot);

  up_all<<<UP_GRID, 512, 0, stream>>>(xb, wsinT, vsinT, ewinT, evinT, tok_list,
                                      w_list, counts, offs, segs, nseg, hsb, hre);

  // ws_out/e_wout transposes overwrite wsinT/ewinT (dead after up_all).
  prep2<<<2304, 256, 0, stream>>>(ws_out, e_wout, wsoutT, ewoutT);

  // down: shared jobs plain-store out; routed jobs plain-store hrd (=evinT).
  down_all<<<DN_GRID, 512, 0, stream>>>(hsb, wsoutT, hre, ewoutT, tok_list,
                                        counts, offs, segs, nseg, out, hrd);
  finish_add<<<TOK * DIM / 8 / 256, 256, 0, stream>>>(hrd, pair_slot, out);
}

// Round 17
// 133.867 us; speedup vs baseline: 1.1743x; 1.0733x over previous
//
#include <hip/hip_runtime.h>
#include <hip/hip_bf16.h>
#include <math.h>

typedef __attribute__((ext_vector_type(4))) float f32x4;
typedef __attribute__((ext_vector_type(8))) short s16x8;
typedef __hip_bfloat16 bf16;

constexpr int TOK = 2048;   // B*S tokens
constexpr int DIM = 1024;   // hidden D
constexpr int HID = 512;    // expert inter H
constexpr int NE  = 16;     // experts
constexpr int NK  = 4;      // top-k
constexpr int NHS = 1024;   // shared inter HS
constexpr int NPAIR = TOK * NK;  // 8192 token-expert pairs

// Per-XCD job capacities (worst-case routing: expert pair cnt sum <= 4096
// -> nseg sum <= 32 -> 128 routed jobs + 16/8 shared).
constexpr int CPX_UP = 144;
constexpr int CPX_DN = 136;
constexpr int UP_GRID = 8 * CPX_UP;  // 1152
constexpr int DN_GRID = 8 * CPX_DN;  // 1088

#define MFMA(a, b, c) __builtin_amdgcn_mfma_f32_16x16x32_bf16(a, b, c, 0, 0, 0)

#define GLOAD_LDS(gp, lp)                                                        \
  __builtin_amdgcn_global_load_lds(                                              \
      (const __attribute__((address_space(1))) unsigned int*)(gp),               \
      (__attribute__((address_space(3))) unsigned int*)(lp), 16, 0, 0)

// Stage a (CH*64)-row x 64-col bf16 tile into LDS with 512 threads. rp[i] is
// this thread's precomputed row base pointer. LDS slot s of row r holds
// k-chunk s^(r&7): XOR swizzle on the per-lane GLOBAL source; LDS dest linear
// (global_load_lds requirement). 0 bank conflicts measured rounds 2-16.
template <int CH>
static __device__ __forceinline__ void stage_p(const bf16* const* rp, int k0,
                                               bf16* lds, int tid) {
  int wid = tid >> 6;
#pragma unroll
  for (int i = 0; i < CH; ++i) {
    int c = i * 512 + tid;      // 16B-chunk index
    int row = c >> 3;
    int slot = c & 7;
    int j = slot ^ (row & 7);
    const bf16* g = rp[i] + k0 + j * 8;
    bf16* l = lds + (size_t)(i * 512 + wid * 64) * 8;  // wave-uniform base
    GLOAD_LDS(g, l);
  }
}

static __device__ __forceinline__ s16x8 frag(const bf16* lds, int row, int kc) {
  return *(const s16x8*)(lds + row * 64 + ((kc ^ (row & 7)) << 3));
}

static __device__ __forceinline__ float b2f(short u) {
  union { unsigned int i; float f; } c;
  c.i = ((unsigned int)(unsigned short)u) << 16;
  return c.f;
}

struct bf16x4 { bf16 a, b, c, d; };
struct alignas(16) bf16x8 { bf16 v[8]; };

// ---------------- vectorized transpose+cast: 64x64 tiles ----------------

static __device__ __forceinline__ void tr64(const float* __restrict__ src,
                                            bf16* __restrict__ dst, int R, int C,
                                            int bx, int by, float (*t)[65], int tid) {
  int r0 = by * 64, c0 = bx * 64;
#pragma unroll
  for (int i = 0; i < 4; ++i) {
    int row = i * 16 + (tid >> 4);
    int col = (tid & 15) * 4;
    float4 v = *(const float4*)(src + (size_t)(r0 + row) * C + c0 + col);
    t[row][col] = v.x; t[row][col + 1] = v.y;
    t[row][col + 2] = v.z; t[row][col + 3] = v.w;
  }
  __syncthreads();
  int c = tid >> 2;             // out-row (source col) 0..63
  int rb = (tid & 3) * 16;      // source-row base
  bf16x8 o0, o1;
#pragma unroll
  for (int k = 0; k < 8; ++k) o0.v[k] = __float2bfloat16(t[rb + k][c]);
#pragma unroll
  for (int k = 0; k < 8; ++k) o1.v[k] = __float2bfloat16(t[rb + 8 + k][c]);
  bf16* d = dst + (size_t)(c0 + c) * R + r0 + rb;
  *(bf16x8*)d = o0;
  *(bf16x8*)(d + 8) = o1;
}

// ---------------- prep1 + fused gate (independent block ranges) -------------
// Blocks [0,512): gate scores (fp32 exact) + x->bf16 cast, 4 tokens/block.
// Blocks [512, 5120): weight transposes for the up-projection.

__global__ __launch_bounds__(256) void prep1_gate(
    const float* __restrict__ x, const float* __restrict__ gw,
    bf16* __restrict__ xb, float* __restrict__ scores,
    const float* __restrict__ ws_in, const float* __restrict__ vs_in,
    const float* __restrict__ e_win, const float* __restrict__ e_vin,
    bf16* __restrict__ wsinT, bf16* __restrict__ vsinT,
    bf16* __restrict__ ewinT, bf16* __restrict__ evinT) {
  __shared__ float t[64][65];
  int bid = blockIdx.x, tid = threadIdx.x;
  if (bid < 512) {
    int lane = tid & 63, wid = tid >> 6;
    int tok = bid * 4 + wid;
    const float* xr = x + (size_t)tok * DIM + lane * 16;
    float4 x4[4];
#pragma unroll
    for (int q = 0; q < 4; ++q) x4[q] = *(const float4*)(xr + q * 4);
    bf16* xo = xb + (size_t)tok * DIM + lane * 16;
#pragma unroll
    for (int q = 0; q < 4; ++q) {
      bf16x4 o{__float2bfloat16(x4[q].x), __float2bfloat16(x4[q].y),
               __float2bfloat16(x4[q].z), __float2bfloat16(x4[q].w)};
      *reinterpret_cast<bf16x4*>(xo + q * 4) = o;
    }
    float s[NE];
#pragma unroll
    for (int e = 0; e < NE; ++e) {
      const float* wr_ = gw + (size_t)e * DIM + lane * 16;
      float a = 0.f;
#pragma unroll
      for (int q = 0; q < 4; ++q) {
        float4 w4 = *(const float4*)(wr_ + q * 4);
        a += x4[q].x * w4.x + x4[q].y * w4.y + x4[q].z * w4.z + x4[q].w * w4.w;
      }
      s[e] = a;
    }
#pragma unroll
    for (int e = 0; e < NE; ++e)
#pragma unroll
      for (int off = 32; off; off >>= 1) s[e] += __shfl_xor(s[e], off);
    if (lane == 0) {
#pragma unroll
      for (int e = 0; e < NE; ++e) scores[(size_t)tok * NE + e] = s[e];
    }
    return;
  }
  int b0 = bid - 512;
  if (b0 < 256) {
    tr64(ws_in, wsinT, DIM, NHS, b0 & 15, b0 >> 4, t, tid);
  } else if (b0 < 512) {
    int b = b0 - 256;
    tr64(vs_in, vsinT, DIM, NHS, b & 15, b >> 4, t, tid);
  } else if (b0 < 2560) {
    int b = b0 - 512, e = b >> 7; b &= 127;
    tr64(e_win + (size_t)e * DIM * HID, ewinT + (size_t)e * DIM * HID,
         DIM, HID, b & 7, b >> 3, t, tid);
  } else {
    int b = b0 - 2560, e = b >> 7; b &= 127;
    tr64(e_vin + (size_t)e * DIM * HID, evinT + (size_t)e * DIM * HID,
         DIM, HID, b & 7, b >> 3, t, tid);
  }
}

__global__ __launch_bounds__(256) void prep2(const float* __restrict__ ws_out,
                                             const float* __restrict__ e_wout,
                                             bf16* __restrict__ wsoutT,
                                             bf16* __restrict__ ewoutT) {
  __shared__ float t[64][65];
  int bid = blockIdx.x, tid = threadIdx.x;
  if (bid < 256) {
    tr64(ws_out, wsoutT, NHS, DIM, bid & 15, bid >> 4, t, tid);
  } else {
    int b = bid - 256, e = b >> 7; b &= 127;
    tr64(e_wout + (size_t)e * HID * DIM, ewoutT + (size_t)e * HID * DIM,
         HID, DIM, b & 15, b >> 4, t, tid);
  }
}

// One THREAD per token: sigmoid + top-4 + LDS histogram -> 16 atomics/block.
__global__ __launch_bounds__(256) void topk_hist(const float* __restrict__ scores,
                                                 int* __restrict__ topi,
                                                 float* __restrict__ topw,
                                                 int* __restrict__ counts) {
  __shared__ int h[NE];
  int tid = threadIdx.x;
  int t = blockIdx.x * 256 + tid;
  if (tid < NE) h[tid] = 0;
  __syncthreads();
  float g[NE];
  const float* sr = scores + (size_t)t * NE;
#pragma unroll
  for (int q = 0; q < 4; ++q) {
    float4 v = *(const float4*)(sr + q * 4);
    g[q * 4 + 0] = 1.f / (1.f + expf(-v.x));
    g[q * 4 + 1] = 1.f / (1.f + expf(-v.y));
    g[q * 4 + 2] = 1.f / (1.f + expf(-v.z));
    g[q * 4 + 3] = 1.f / (1.f + expf(-v.w));
  }
  unsigned used = 0;
  int bi[NK]; float bv[NK];
  float sum = 0.f;
#pragma unroll
  for (int j = 0; j < NK; ++j) {        // lax.top_k tie-break: lowest index first
    int best = 0; float v = -1e30f;
#pragma unroll
    for (int e = 0; e < NE; ++e)
      if (!((used >> e) & 1u) && g[e] > v) { v = g[e]; best = e; }
    used |= 1u << best; bi[j] = best; bv[j] = v; sum += v;
  }
  float inv = 1.f / sum;
#pragma unroll
  for (int j = 0; j < NK; ++j) {
    topi[t * NK + j] = bi[j];
    topw[t * NK + j] = bv[j] * inv;
    atomicAdd(&h[bi[j]], 1);
  }
  __syncthreads();
  if (tid < NE) atomicAdd(&counts[tid], h[tid]);
}

// Offsets + XCD-partitioned job lists. 64 threads, parallel writes.
// Job encoding: shared = 0x40000000 | (m<<4) | n0; routed = (e<<8)|(seg<<4)|n0.
// jobs arrays pre-memset to -1 (empty); block exits on jv<0.
__global__ __launch_bounds__(64) void route_small(const int* __restrict__ counts,
                                                  int* __restrict__ offs,
                                                  int* __restrict__ cursor,
                                                  int* __restrict__ jobs_up,
                                                  int* __restrict__ jobs_dn) {
  __shared__ int nseg_s[NE], off_s[NE];
  int t = threadIdx.x;
  if (t == 0) {
    int o = 0;
    for (int e = 0; e < NE; ++e) { off_s[e] = o; o += counts[e]; }
  }
  __syncthreads();
  if (t < NE) {
    offs[t] = off_s[t];
    cursor[t * 32] = 0;
    nseg_s[t] = (counts[t] + 127) >> 7;
  }
  __syncthreads();
  if (t < 16) {            // up-shared: 16 groups of (4m x 2n)
    int g = t, chunk = g & 7, base = (g >> 3) * 8;
    for (int w = 0; w < 8; ++w) {
      int m = (g >> 2) * 4 + (w >> 1);
      int n0 = (g & 3) * 2 + (w & 1);
      jobs_up[chunk * CPX_UP + base + w] = 0x40000000 | (m << 4) | n0;
    }
  } else if (t < 32) {     // up-routed: expert e on XCD e&7
    int e = t - 16, chunk = e & 7;
    int base = 16 + ((e >= 8) ? 4 * nseg_s[e - 8] : 0);
    for (int s = 0; s < nseg_s[e]; ++s)
      for (int n = 0; n < 4; ++n)
        jobs_up[chunk * CPX_UP + base + s * 4 + n] = (e << 8) | (s << 4) | n;
  } else if (t < 40) {     // down-shared: 8 groups of (4m x 2n)
    int g = t - 32, chunk = g;
    for (int w = 0; w < 8; ++w) {
      int m = (g >> 1) * 4 + (w >> 1);
      int n0 = (g & 1) * 2 + (w & 1);
      jobs_dn[chunk * CPX_DN + w] = 0x40000000 | (m << 4) | n0;
    }
  } else if (t < 56) {     // down-routed
    int e = t - 40, chunk = e & 7;
    int base = 8 + ((e >= 8) ? 4 * nseg_s[e - 8] : 0);
    for (int s = 0; s < nseg_s[e]; ++s)
      for (int n = 0; n < 4; ++n)
        jobs_dn[chunk * CPX_DN + base + s * 4 + n] = (e << 8) | (s << 4) | n;
  }
}

// Parallel compaction via per-expert atomic cursor (cacheline-padded).
__global__ __launch_bounds__(256) void scatter_pairs(const int* __restrict__ topi,
                                                     const float* __restrict__ topw,
                                                     const int* __restrict__ offs,
                                                     int* __restrict__ cursor,
                                                     int* __restrict__ tok_list,
                                                     float* __restrict__ w_list,
                                                     int* __restrict__ pair_slot) {
  int p = blockIdx.x * 256 + threadIdx.x;
  if (p >= NPAIR) return;
  int e = topi[p];
  int rank = atomicAdd(&cursor[e * 32], 1);
  int slot = offs[e] + rank;
  tok_list[slot] = p >> 2;   // token id
  w_list[slot] = topw[p];
  pair_slot[p] = slot;
}

// ---------------- fused up-projection: r13 pipeline + XCD job map -----------
// 128x256 tile, 8 waves (2Mx4N), 80 KB LDS: A single + B double-buffered.
// Per K-step: issue B(k+1) -> wait vmcnt(4) -> barrier -> MFMA -> barrier ->
// stage A(k+1). B' interleaves W1/W2 rows 16-at-a-time.

__global__ __launch_bounds__(512, 4) void up_all(
    const bf16* __restrict__ xb, const bf16* __restrict__ wsinT,
    const bf16* __restrict__ vsinT, const bf16* __restrict__ ewinT,
    const bf16* __restrict__ evinT, const int* __restrict__ tok_list,
    const float* __restrict__ w_list, const int* __restrict__ counts,
    const int* __restrict__ offs, const int* __restrict__ jobs_up,
    bf16* __restrict__ hsb, bf16* __restrict__ hre) {
  int bid = blockIdx.x;
  int jv = jobs_up[(bid & 7) * CPX_UP + (bid >> 3)];
  if (jv < 0) return;
  int tid = threadIdx.x, lane = tid & 63, wid = tid >> 6;
  int wr = wid >> 2, wc = wid & 3;

  bool is_shared = (jv & 0x40000000) != 0;
  int m0, n0, cnt = TOK, off_e = 0;
  const bf16 *w1, *w2;
  if (is_shared) {
    m0 = ((jv >> 4) & 15) * 128; n0 = jv & 15;
    w1 = wsinT; w2 = vsinT;
  } else {
    int e = (jv >> 8) & 15;
    m0 = ((jv >> 4) & 15) * 128; n0 = jv & 15;
    cnt = counts[e]; off_e = offs[e];
    w1 = ewinT + (size_t)e * HID * DIM;
    w2 = evinT + (size_t)e * HID * DIM;
  }

  const bf16* ap[2]; const bf16* bp[4];
#pragma unroll
  for (int i = 0; i < 2; ++i) {
    int row = (i * 512 + tid) >> 3;  // 0..127
    int gr = is_shared ? (m0 + row) : tok_list[off_e + min(m0 + row, cnt - 1)];
    ap[i] = xb + (size_t)gr * DIM;
  }
#pragma unroll
  for (int i = 0; i < 4; ++i) {
    int r = (i * 512 + tid) >> 3;    // B'-row 0..255
    int ridx = n0 * 128 + (r >> 5) * 16 + (r & 15);
    bp[i] = ((r & 16) ? w2 : w1) + (size_t)ridx * DIM;
  }

  __shared__ alignas(16) bf16 As[128 * 64], Bs[2][256 * 64];
  f32x4 acc[4][4];
  f32x4 z4 = {0.f, 0.f, 0.f, 0.f};
#pragma unroll
  for (int m = 0; m < 4; ++m)
#pragma unroll
    for (int q = 0; q < 4; ++q) acc[m][q] = z4;

  constexpr int NT = DIM / 64;  // 16
  stage_p<2>(ap, 0, As, tid);
  stage_p<4>(bp, 0, Bs[0], tid);

  for (int kt = 0; kt < NT; ++kt) {
    if (kt + 1 < NT) {
      stage_p<4>(bp, (kt + 1) * 64, Bs[(kt + 1) & 1], tid);
      asm volatile("s_waitcnt vmcnt(4)" ::: "memory");   // B(k+1) stays in flight
    } else {
      asm volatile("s_waitcnt vmcnt(0)" ::: "memory");
    }
    __builtin_amdgcn_sched_barrier(0);
    __builtin_amdgcn_s_barrier();
    __builtin_amdgcn_sched_barrier(0);
    const bf16* Bc = Bs[kt & 1];
    __builtin_amdgcn_s_setprio(1);
#pragma unroll
    for (int ks = 0; ks < 2; ++ks) {
      int r16 = lane & 15, kc = (ks << 2) + (lane >> 4);
      s16x8 a[4];
#pragma unroll
      for (int m = 0; m < 4; ++m) a[m] = frag(As, wr * 64 + m * 16 + r16, kc);
#pragma unroll
      for (int q = 0; q < 4; ++q) {
        s16x8 b = frag(Bc, wc * 64 + q * 16 + r16, kc);
#pragma unroll
        for (int m = 0; m < 4; ++m) acc[m][q] = MFMA(a[m], b, acc[m][q]);
      }
    }
    __builtin_amdgcn_s_setprio(0);
    __builtin_amdgcn_sched_barrier(0);
    __builtin_amdgcn_s_barrier();
    __builtin_amdgcn_sched_barrier(0);
    if (kt + 1 < NT) stage_p<2>(ap, (kt + 1) * 64, As, tid);
  }
#pragma unroll
  for (int m = 0; m < 4; ++m)
#pragma unroll
    for (int q = 0; q < 4; q += 2) {
      int c = n0 * 128 + (wc * 2 + (q >> 1)) * 16 + (lane & 15);
#pragma unroll
      for (int i = 0; i < 4; ++i) {
        int r = wr * 64 + m * 16 + (lane >> 4) * 4 + i;
        float z = acc[m][q][i], v = acc[m][q + 1][i];
        float h = z / (1.f + __expf(-z)) * v;
        if (is_shared) {
          hsb[(size_t)(m0 + r) * NHS + c] = __float2bfloat16(h);
        } else {
          int gr = m0 + r;
          if (gr < cnt)
            hre[(size_t)(off_e + gr) * HID + c] =
                __float2bfloat16(h * w_list[off_e + gr]);
        }
      }
    }
}

// ---------------- fused down-projection: r13 pipeline + XCD job map ---------
// Shared jobs plain-store their unique 128x256 out tile; routed jobs store
// bf16 rows into hrd[slot][DIM] (aliases dead evinT); finish_add reduces.

__global__ __launch_bounds__(512, 4) void down_all(
    const bf16* __restrict__ hsb, const bf16* __restrict__ wsoutT,
    const bf16* __restrict__ hre, const bf16* __restrict__ ewoutT,
    const int* __restrict__ tok_list, const int* __restrict__ counts,
    const int* __restrict__ offs, const int* __restrict__ jobs_dn,
    float* __restrict__ out, bf16* __restrict__ hrd) {
  int bid = blockIdx.x;
  int jv = jobs_dn[(bid & 7) * CPX_DN + (bid >> 3)];
  if (jv < 0) return;
  int tid = threadIdx.x, lane = tid & 63, wid = tid >> 6;
  int wr = wid >> 2, wc = wid & 3;

  bool is_shared = (jv & 0x40000000) != 0;
  int m0, n0, cnt = TOK, off_e = 0, K, ldA, ldB;
  const bf16 *Abase, *Bbase;
  if (is_shared) {
    m0 = ((jv >> 4) & 15) * 128; n0 = jv & 15;
    Abase = hsb; ldA = NHS; K = NHS;
    Bbase = wsoutT; ldB = NHS;
  } else {
    int e = (jv >> 8) & 15;
    m0 = ((jv >> 4) & 15) * 128; n0 = jv & 15;
    cnt = counts[e]; off_e = offs[e];
    Abase = hre + (size_t)off_e * HID; ldA = HID; K = HID;
    Bbase = ewoutT + (size_t)e * DIM * HID; ldB = HID;
  }

  const bf16* ap[2]; const bf16* bp[4];
#pragma unroll
  for (int i = 0; i < 2; ++i) {
    int row = (i * 512 + tid) >> 3;  // 0..127
    int gr = is_shared ? (m0 + row) : min(m0 + row, cnt - 1);
    ap[i] = Abase + (size_t)gr * ldA;
  }
#pragma unroll
  for (int i = 0; i < 4; ++i) {
    int r = (i * 512 + tid) >> 3;    // 0..255
    bp[i] = Bbase + (size_t)(n0 * 256 + r) * ldB;
  }

  __shared__ alignas(16) bf16 As[128 * 64], Bs[2][256 * 64];
  f32x4 acc[4][4];
  f32x4 z4 = {0.f, 0.f, 0.f, 0.f};
#pragma unroll
  for (int m = 0; m < 4; ++m)
#pragma unroll
    for (int q = 0; q < 4; ++q) acc[m][q] = z4;

  int NT = K / 64;
  stage_p<2>(ap, 0, As, tid);
  stage_p<4>(bp, 0, Bs[0], tid);

  for (int kt = 0; kt < NT; ++kt) {
    if (kt + 1 < NT) {
      stage_p<4>(bp, (kt + 1) * 64, Bs[(kt + 1) & 1], tid);
      asm volatile("s_waitcnt vmcnt(4)" ::: "memory");
    } else {
      asm volatile("s_waitcnt vmcnt(0)" ::: "memory");
    }
    __builtin_amdgcn_sched_barrier(0);
    __builtin_amdgcn_s_barrier();
    __builtin_amdgcn_sched_barrier(0);
    const bf16* Bc = Bs[kt & 1];
    __builtin_amdgcn_s_setprio(1);
#pragma unroll
    for (int ks = 0; ks < 2; ++ks) {
      int r16 = lane & 15, kc = (ks << 2) + (lane >> 4);
      s16x8 a[4];
#pragma unroll
      for (int m = 0; m < 4; ++m) a[m] = frag(As, wr * 64 + m * 16 + r16, kc);
#pragma unroll
      for (int q = 0; q < 4; ++q) {
        s16x8 b = frag(Bc, wc * 64 + q * 16 + r16, kc);
#pragma unroll
        for (int m = 0; m < 4; ++m) acc[m][q] = MFMA(a[m], b, acc[m][q]);
      }
    }
    __builtin_amdgcn_s_setprio(0);
    __builtin_amdgcn_sched_barrier(0);
    __builtin_amdgcn_s_barrier();
    __builtin_amdgcn_sched_barrier(0);
    if (kt + 1 < NT) stage_p<2>(ap, (kt + 1) * 64, As, tid);
  }
#pragma unroll
  for (int m = 0; m < 4; ++m)
#pragma unroll
    for (int q = 0; q < 4; ++q) {
      int c = n0 * 256 + wc * 64 + q * 16 + (lane & 15);
#pragma unroll
      for (int i = 0; i < 4; ++i) {
        int r = wr * 64 + m * 16 + (lane >> 4) * 4 + i;
        if (is_shared) {
          out[(size_t)(m0 + r) * DIM + c] = acc[m][q][i];
        } else {
          int gr = m0 + r;
          if (gr < cnt)
            hrd[(size_t)(off_e + gr) * DIM + c] = __float2bfloat16(acc[m][q][i]);
        }
      }
    }
}

// ---------------- final gather-reduce: out[t] += sum of 4 routed rows -------

__global__ __launch_bounds__(256) void finish_add(const bf16* __restrict__ hrd,
                                                  const int* __restrict__ pair_slot,
                                                  float* __restrict__ out) {
  int idx = blockIdx.x * 256 + threadIdx.x;
  int t = idx >> 7;            // DIM/8 = 128 chunks per token
  int c0 = (idx & 127) * 8;
  int4 s4 = *(const int4*)(pair_slot + t * 4);
  float acc[8];
  float* o = out + (size_t)t * DIM + c0;
#pragma unroll
  for (int k = 0; k < 8; ++k) acc[k] = o[k];
  int sl[4] = {s4.x, s4.y, s4.z, s4.w};
#pragma unroll
  for (int j = 0; j < 4; ++j) {
    s16x8 v = *(const s16x8*)(hrd + (size_t)sl[j] * DIM + c0);
#pragma unroll
    for (int k = 0; k < 8; ++k) acc[k] += b2f(v[k]);
  }
#pragma unroll
  for (int k = 0; k < 8; ++k) o[k] = acc[k];
}

// ---------------- launcher ----------------

extern "C" void kernel_launch(void* const* d_in, const int* in_sizes, int n_in,
                              void* d_out, int out_size, void* d_ws, size_t ws_size,
                              hipStream_t stream) {
  const float* x      = (const float*)d_in[0];
  const float* gw     = (const float*)d_in[1];
  const float* ws_in  = (const float*)d_in[2];
  const float* vs_in  = (const float*)d_in[3];
  const float* ws_out = (const float*)d_in[4];
  const float* e_win  = (const float*)d_in[5];
  const float* e_vin  = (const float*)d_in[6];
  const float* e_wout = (const float*)d_in[7];
  float* out = (float*)d_out;

  // Workspace layout, peak ~52.7 MB (validated fits in rounds 2-16).
  char* p = (char*)d_ws;
  bf16* xb     = (bf16*)p;  p += (size_t)TOK * DIM * 2;            // 4 MB
  bf16* wsinT  = (bf16*)p;                                         // 2 MB
  bf16* wsoutT = wsinT;                                            // reused after up_all
  p += (size_t)NHS * DIM * 2;
  bf16* vsinT  = (bf16*)p;  p += (size_t)NHS * DIM * 2;            // 2 MB
  bf16* hsb    = (bf16*)p;  p += (size_t)TOK * NHS * 2;            // 4 MB
  bf16* ewinT  = (bf16*)p;                                         // 16 MB
  bf16* ewoutT = ewinT;                                            // reused after up_all
  p += (size_t)NE * DIM * HID * 2;
  bf16* evinT  = (bf16*)p;                                         // 16 MB
  bf16* hrd    = evinT;  // routed down-proj rows; NPAIR*DIM*2 = exactly 16 MiB
  p += (size_t)NE * DIM * HID * 2;
  bf16* hre    = (bf16*)p;  p += (size_t)(NPAIR + 128) * HID * 2;  // 8.25 MB
  int*   topi      = (int*)p;    p += (size_t)NPAIR * 4;
  float* topw      = (float*)p;  p += (size_t)NPAIR * 4;
  int*   tok_list  = (int*)p;    p += (size_t)NPAIR * 4;
  float* w_list    = (float*)p;  p += (size_t)NPAIR * 4;
  int*   pair_slot = (int*)p;    p += (size_t)NPAIR * 4;
  float* scores    = (float*)p;  p += (size_t)TOK * NE * 4;        // 128 KB
  int*   counts    = (int*)p;    p += 64;
  int*   offs      = (int*)p;    p += 64;
  int*   cursor    = (int*)p;    p += NE * 32 * 4;                 // 1 line/expert
  int*   jobs_up   = (int*)p;    p += UP_GRID * 4;
  int*   jobs_dn   = (int*)p;    p += DN_GRID * 4;

  hipMemsetAsync(counts, 0, NE * sizeof(int), stream);
  hipMemsetAsync(jobs_up, 0xFF, UP_GRID * sizeof(int), stream);
  hipMemsetAsync(jobs_dn, 0xFF, DN_GRID * sizeof(int), stream);

  prep1_gate<<<5120, 256, 0, stream>>>(x, gw, xb, scores, ws_in, vs_in,
                                       e_win, e_vin, wsinT, vsinT, ewinT, evinT);
  topk_hist<<<TOK / 256, 256, 0, stream>>>(scores, topi, topw, counts);
  route_small<<<1, 64, 0, stream>>>(counts, offs, cursor, jobs_up, jobs_dn);
  scatter_pairs<<<NPAIR / 256, 256, 0, stream>>>(topi, topw, offs, cursor,
                                                 tok_list, w_list, pair_slot);

  up_all<<<UP_GRID, 512, 0, stream>>>(xb, wsinT, vsinT, ewinT, evinT, tok_list,
                                      w_list, counts, offs, jobs_up, hsb, hre);

  // ws_out/e_wout transposes overwrite wsinT/ewinT (dead after up_all).
  prep2<<<2304, 256, 0, stream>>>(ws_out, e_wout, wsoutT, ewoutT);

  // down: shared jobs plain-store out; routed jobs plain-store hrd (=evinT).
  down_all<<<DN_GRID, 512, 0, stream>>>(hsb, wsoutT, hre, ewoutT, tok_list,
                                        counts, offs, jobs_dn, out, hrd);
  finish_add<<<TOK * DIM / 8 / 256, 256, 0, stream>>>(hrd, pair_slot, out);
}